// Round 22
// baseline (177.129 us; speedup 1.0000x reference)
//
#include <hip/hip_runtime.h>
#include <hip/hip_bf16.h>
#include <stdint.h>

typedef __attribute__((ext_vector_type(4))) float f32x4;
typedef __attribute__((ext_vector_type(8))) short s16x8;
typedef __attribute__((ext_vector_type(4))) short s16x4;
typedef __attribute__((ext_vector_type(8))) unsigned short u16x8;

#define NB 8
#define HH 56
#define WW0 56
#define NC 384
#define NQTOK (HH*WW0)     // 3136
#define NKTOK 784
#define NHEAD 6
#define HDIM 64
// scale folded into q-conv: (1/sqrt(64)) * log2(e)
#define QSCALE 0.18033688f

__device__ __forceinline__ float bf2f(unsigned short u) {
    union { unsigned int i; float f; } x; x.i = ((unsigned int)u) << 16; return x.f;
}
__device__ __forceinline__ unsigned short f2bf(float f) {
    union { float f; unsigned int i; } x; x.f = f;
    unsigned int r = x.i + 0x7FFFu + ((x.i >> 16) & 1u);
    return (unsigned short)(r >> 16);
}
// round-half-up bf16: 2 ops vs RNE's 5; differs only on exact ties (P-packing only)
__device__ __forceinline__ unsigned short f2bf_rn(float f) {
    union { float f; unsigned int i; } x; x.f = f;
    return (unsigned short)((x.i + 0x8000u) >> 16);
}

// ---------- fused prep kernel (range-dispatched) ----------
__global__ __launch_bounds__(256) void prep_all(
    const float* __restrict__ x,
    const float* __restrict__ qw, const float* __restrict__ kw,
    const float* __restrict__ vw, const float* __restrict__ pw,
    const float* __restrict__ qb, const float* __restrict__ kb,
    const float* __restrict__ vb, const float* __restrict__ pb,
    const float* __restrict__ qdw, const float* __restrict__ kdw, const float* __restrict__ vdw,
    unsigned short* __restrict__ xbf, unsigned short* __restrict__ wbf,
    float* __restrict__ wtab, float* __restrict__ ball)
{
    const int bid = blockIdx.x;
    const int t = threadIdx.x;
    if (bid < 4704) {
        int i = bid*256 + t;
        f32x4 a0 = *(const f32x4*)&x[(size_t)i*8];
        f32x4 a1 = *(const f32x4*)&x[(size_t)i*8 + 4];
        u16x8 p;
        #pragma unroll
        for (int j = 0; j < 4; ++j) { p[j] = f2bf(a0[j]); p[j+4] = f2bf(a1[j]); }
        *(u16x8*)&xbf[(size_t)i*8] = p;
    } else if (bid < 4992) {
        int i = (bid - 4704)*256 + t;
        int m = i / 18432;
        const float* s = (m==0) ? qw : ((m==1) ? kw : ((m==2) ? vw : pw));
        int r = i - m*18432;
        f32x4 a0 = *(const f32x4*)&s[(size_t)r*8];
        f32x4 a1 = *(const f32x4*)&s[(size_t)r*8 + 4];
        u16x8 p;
        #pragma unroll
        for (int j = 0; j < 4; ++j) { p[j] = f2bf(a0[j]); p[j+4] = f2bf(a1[j]); }
        *(u16x8*)&wbf[(size_t)i*8] = p;
    } else {
        int j = (bid - 4992)*256 + t;
        if (j < 3*9*NC) {
            int m = j / (9*NC); int r = j - m*(9*NC);
            int tap = r / NC; int c = r - tap*NC;
            const float* src = (m==0) ? qdw : ((m==1) ? kdw : vdw);
            wtab[j] = src[c*9 + tap];
        } else {
            int jj = j - 3*9*NC;
            if (jj < 4*NC) {
                int m = jj / NC, r = jj - m*NC;
                ball[jj] = ((m==0) ? qb : ((m==1) ? kb : ((m==2) ? vb : pb)))[r];
            }
        }
    }
}

// ---------- GEMM: 256x128 tile, BK=64, 8 waves (4x2), XOR-swizzled LDS ----------
template<bool OUT_F32>
__global__ __launch_bounds__(512) void gemm_bt_bf(
    const unsigned short* __restrict__ A,
    const unsigned short* __restrict__ Wall,  // [nmat][384*384] bf16
    const float* __restrict__ Ball,           // [nmat][384] f32
    unsigned short* __restrict__ Oa, unsigned short* __restrict__ Ob, unsigned short* __restrict__ Oc,
    float* __restrict__ Of,
    int ntiles)
{
    __shared__ unsigned short lA[256*64];   // 32 KB
    __shared__ unsigned short lW[128*64];   // 16 KB
    char* lAb = (char*)lA;
    char* lWb = (char*)lW;
    const int bid = blockIdx.x;
    const int nt = bid % ntiles;      // nt-major: A-tile reuse temporally local
    const int mt = bid / ntiles;
    const int mat = nt / 3;
    const int ncol = nt - mat*3;
    const unsigned short* W = Wall + (size_t)mat*NC*NC;
    const float* Bsel = Ball + mat*NC;
    unsigned short* Osel = (mat==0) ? Oa : ((mat==1) ? Ob : Oc);
    const int Mbase = mt*256, Nbase = ncol*128;
    const int t = threadIdx.x;
    const int w = t >> 6, l = t & 63;
    const int wr = w >> 1, wc = w & 1;       // wr 0..3, wc 0..1
    const int lr = l & 15, lg = l >> 4;
    const int swg = (lr & 7) << 4;

    f32x4 acc[4][4] = {};
    for (int kt = 0; kt < 6; ++kt) {
        __syncthreads();
        #pragma unroll
        for (int i = 0; i < 4; ++i) {        // A: 2048 chunks of 16B
            int c = i*512 + t;
            int row = c >> 3, c8 = c & 7;
            int sdst = row*128 + ((c8*16) ^ ((row & 7) << 4));
            *(u16x8*)(lAb + sdst) = *(const u16x8*)&A[(size_t)(Mbase+row)*NC + kt*64 + c8*8];
        }
        #pragma unroll
        for (int i = 0; i < 2; ++i) {        // W: 1024 chunks
            int c = i*512 + t;
            int row = c >> 3, c8 = c & 7;
            int sdst = row*128 + ((c8*16) ^ ((row & 7) << 4));
            *(u16x8*)(lWb + sdst) = *(const u16x8*)&W[(size_t)(Nbase+row)*NC + kt*64 + c8*8];
        }
        __syncthreads();
        #pragma unroll
        for (int kk = 0; kk < 2; ++kk) {
            s16x8 af[4], bfr[4];
            #pragma unroll
            for (int m = 0; m < 4; ++m)
                af[m] = *(const s16x8*)(lAb + (wr*64 + m*16 + lr)*128 + ((kk*64 + lg*16) ^ swg));
            #pragma unroll
            for (int n = 0; n < 4; ++n)
                bfr[n] = *(const s16x8*)(lWb + (wc*64 + n*16 + lr)*128 + ((kk*64 + lg*16) ^ swg));
            #pragma unroll
            for (int m = 0; m < 4; ++m)
                #pragma unroll
                for (int n = 0; n < 4; ++n)
                    acc[m][n] = __builtin_amdgcn_mfma_f32_16x16x32_bf16(af[m], bfr[n], acc[m][n], 0, 0, 0);
        }
    }
    #pragma unroll
    for (int n = 0; n < 4; ++n) {
        int col = Nbase + wc*64 + n*16 + lr;
        float bias = Bsel[col];
        #pragma unroll
        for (int m = 0; m < 4; ++m) {
            int row0 = Mbase + wr*64 + m*16 + lg*4;
            #pragma unroll
            for (int r = 0; r < 4; ++r) {
                float vv = acc[m][n][r] + bias;
                if (OUT_F32) Of[(size_t)(row0 + r)*NC + col] = vv;
                else Osel[(size_t)(row0 + r)*NC + col] = f2bf(vv);
            }
        }
    }
}

// ---------- depthwise conv body (shared) ----------
// MODE: 0 = token layout (b,tok,384); 1 = head-packed K (bh,tok,64); 2 = transposed V (bh,d,tok)
template<int S, int HO, int WO, bool SCALE, int MODE>
__device__ __forceinline__ void dwconv_body(
    int idx,
    const unsigned short* __restrict__ in,
    const float* __restrict__ wt9,   // (9, NC) transposed
    const float* __restrict__ bias,  // (NC)
    unsigned short* __restrict__ outp)
{
    const int nc8 = NC/8;
    int c8 = idx % nc8; int rest = idx / nc8;
    int wo = rest % WO; rest /= WO;
    int ho = rest % HO; int b = rest / HO;
    int c0 = c8*8;
    f32x4 b0 = *(const f32x4*)&bias[c0];
    f32x4 b1 = *(const f32x4*)&bias[c0+4];
    float acc[8];
    #pragma unroll
    for (int j = 0; j < 4; ++j) { acc[j] = b0[j]; acc[j+4] = b1[j]; }
    #pragma unroll
    for (int kh = 0; kh < 3; ++kh) {
        int h = ho*S + kh - 1;
        if (h < 0 || h >= HH) continue;
        #pragma unroll
        for (int kw = 0; kw < 3; ++kw) {
            int ww = wo*S + kw - 1;
            if (ww < 0 || ww >= WW0) continue;
            int tap = kh*3 + kw;
            u16x8 xv = *(const u16x8*)&in[((size_t)b*(HH*WW0) + h*WW0 + ww)*NC + c0];
            f32x4 w0 = *(const f32x4*)&wt9[tap*NC + c0];
            f32x4 w1 = *(const f32x4*)&wt9[tap*NC + c0 + 4];
            #pragma unroll
            for (int j = 0; j < 4; ++j) {
                acc[j]   += bf2f(xv[j])   * w0[j];
                acc[j+4] += bf2f(xv[j+4]) * w1[j];
            }
        }
    }
    if (SCALE) {
        #pragma unroll
        for (int j = 0; j < 8; ++j) acc[j] *= QSCALE;
    }
    int tok = ho*WO + wo;
    int hh = c0 >> 6, d0 = c0 & 63;
    if (MODE == 0) {
        u16x8 ov;
        #pragma unroll
        for (int j = 0; j < 8; ++j) ov[j] = f2bf(acc[j]);
        *(u16x8*)&outp[((size_t)b*(HO*WO) + tok)*NC + c0] = ov;
    } else if (MODE == 1) {
        u16x8 ov;
        #pragma unroll
        for (int j = 0; j < 8; ++j) ov[j] = f2bf(acc[j]);
        *(u16x8*)&outp[((size_t)(b*NHEAD + hh)*(HO*WO) + tok)*HDIM + d0] = ov;
    } else {
        size_t base = ((size_t)(b*NHEAD + hh)*HDIM + d0)*(HO*WO) + tok;
        #pragma unroll
        for (int j = 0; j < 8; ++j)
            outp[base + (size_t)j*(HO*WO)] = f2bf(acc[j]);
    }
}

// all three convs fused: Qc lives in d_out UPPER half (disjoint from preV in lower half)
__global__ __launch_bounds__(256) void dwconv_all(
    const unsigned short* __restrict__ preK, const unsigned short* __restrict__ preV,
    const unsigned short* __restrict__ preQ,
    const float* __restrict__ wtK, const float* __restrict__ wtV, const float* __restrict__ wtQ,
    const float* __restrict__ biasK, const float* __restrict__ biasV, const float* __restrict__ biasQ,
    unsigned short* __restrict__ Kpk, unsigned short* __restrict__ Vt,
    unsigned short* __restrict__ Qc)
{
    const int bid = blockIdx.x;               // 7056 = 1176 + 1176 + 4704
    if (bid < 1176) {
        int idx = bid*256 + threadIdx.x;
        dwconv_body<2,28,28,false,1>(idx, preK, wtK, biasK, Kpk);
    } else if (bid < 2352) {
        int idx = (bid-1176)*256 + threadIdx.x;
        dwconv_body<2,28,28,false,2>(idx, preV, wtV, biasV, Vt);
    } else {
        int idx = (bid-2352)*256 + threadIdx.x;
        dwconv_body<1,56,56,true,0>(idx, preQ, wtQ, biasQ, Qc);
    }
}

// ---------- attention: 16 q-rows/wave, 16 waves/block (256 q), 624 blocks, KVBLK=64 ----------
// sign(s)*softmax(|s|), no max tracking, per-lane deferred denominator.
// Rotated 2-deep pipeline; XOR swizzle byte^=((row&7)<<4); raw v_exp_f32.
// One staging pass serves 16 waves; each thread stages exactly ONE 16B chunk
// (waves 0-7 -> K, waves 8-15 -> V; wave-uniform). Occupancy cap 2 blocks x 16 = 32 waves/CU.
__global__ __launch_bounds__(1024) void attn_fwd(
    const unsigned short* __restrict__ Q,   // (NB, 3136, 384) bf16 pre-scaled by 0.125*log2e
    const unsigned short* __restrict__ Kpk, // (48, 784, 64) bf16 head-packed
    const unsigned short* __restrict__ Vt,  // (48, 64, 784) bf16 transposed
    unsigned short* __restrict__ ctx)       // (NB, 3136, 384) bf16
{
    __shared__ unsigned short lK[2][4096];
    __shared__ unsigned short lV[2][4096];
    const int bid = blockIdx.x;             // 624 = 8 XCD * 6 bh * 13 qt
    const int xcd = bid & 7, slot = bid >> 3;
    const int bh = xcd*6 + slot/13;
    const int qt = slot % 13;
    const int b = bh / NHEAD, h = bh - b*NHEAD;
    const int t = threadIdx.x;
    const int w = t >> 6, l = t & 63;
    const int lq = l & 15, lg = l >> 4;
    const int wq0 = qt*256 + w*16;          // 13*256 = 3328 > 3136: clamp + skip store
    const int wq0c = (wq0 > NQTOK-16) ? (NQTOK-16) : wq0;

    const unsigned short* Qb = Q + ((size_t)b*NQTOK + wq0c + lq)*NC + h*HDIM;
    s16x8 qA0 = *(const s16x8*)&Qb[lg*8];
    s16x8 qA1 = *(const s16x8*)&Qb[32 + lg*8];

    const char* Kg = (const char*)(Kpk + (size_t)bh*NKTOK*HDIM);
    const char* Vg = (const char*)(Vt + (size_t)bh*HDIM*NKTOK);
    char* lKb = (char*)lK;
    char* lVb = (char*)lV;

    // staging: 512 K-chunks + 512 V-chunks of 16B; ONE chunk per thread
    const int ts = t & 511;
    const int cr = ts >> 3;           // rows 0..63
    const int cc = (ts & 7) * 16;     // byte col in 128B row
    const int dst = cr*128 + (cc ^ ((cr & 7) << 4));
    const bool isK = t < 512;         // wave-uniform (waves 0-7 vs 8-15)

    uint4 rr;
    #define LOADT(kb) do { \
        rr = isK ? *(const uint4*)(Kg + (size_t)((kb) + cr)*128 + cc) \
                 : *(const uint4*)(Vg + (size_t)cr*1568 + (kb)*2 + cc); \
    } while(0)
    #define WRITET(buf) do { \
        *(uint4*)((isK ? lKb : lVb) + (buf)*8192 + dst) = rr; \
    } while(0)

    const int swc = (lq & 7) << 4;
    const int ck0 = (lg*16) ^ swc;          // K frag half 0, byte col
    const int ck1 = (64 + lg*16) ^ swc;     // K frag half 1

    float ls = 0.f;
    f32x4 oacc[4] = {};

    // prologue: tile 0 -> buf0, tile 1 staged in regs
    LOADT(0);
    WRITET(0);
    LOADT(64);
    __syncthreads();

    for (int kt = 0; kt < 12; ++kt) {
        const int cur = kt & 1;
        if (kt < 11) {
            WRITET(cur ^ 1);                 // tile kt+1 (regs loaded last iter)
            if (kt < 10) LOADT((kt+2)*64);   // start loading tile kt+2
        }
        const char* Kl = lKb + cur*8192;
        const char* Vl = lVb + cur*8192;
        f32x4 st[4] = {};
        __builtin_amdgcn_s_setprio(1);
        #pragma unroll
        for (int kfr = 0; kfr < 4; ++kfr) {
            int rb = (kfr*16 + lq)*128;
            s16x8 kf0 = *(const s16x8*)(Kl + rb + ck0);
            s16x8 kf1 = *(const s16x8*)(Kl + rb + ck1);
            st[kfr] = __builtin_amdgcn_mfma_f32_16x16x32_bf16(kf0, qA0, st[kfr], 0,0,0);
            st[kfr] = __builtin_amdgcn_mfma_f32_16x16x32_bf16(kf1, qA1, st[kfr], 0,0,0);
        }
        __builtin_amdgcn_s_setprio(0);
        s16x4 pbv[4];
        {
            float rs = 0.f;
            #pragma unroll
            for (int kfr = 0; kfr < 4; ++kfr)
                #pragma unroll
                for (int r = 0; r < 4; ++r) {
                    float s = st[kfr][r];
                    float e = __builtin_amdgcn_exp2f(fabsf(s));
                    rs += e;
                    pbv[kfr][r] = (short)f2bf_rn(copysignf(e, s));
                }
            ls += rs;
        }
        __builtin_amdgcn_s_setprio(1);
        #pragma unroll
        for (int ks = 0; ks < 4; ++ks)
            #pragma unroll
            for (int f = 0; f < 4; ++f) {
                int va = (f*16 + lq)*128 + ((ks*32 + lg*8) ^ swc);
                s16x4 vvf = *(const s16x4*)(Vl + va);
                oacc[f] = __builtin_amdgcn_mfma_f32_16x16x16bf16_1k(vvf, pbv[ks], oacc[f], 0,0,0);
            }
        __builtin_amdgcn_s_setprio(0);
        if (kt < 11) __syncthreads();
    }
    // tail: k = 768..783 direct from global
    {
        const unsigned short* Kb2 = (const unsigned short*)Kg;
        const unsigned short* Vb2 = (const unsigned short*)Vg;
        const unsigned short* kr = &Kb2[(size_t)(768 + lq)*HDIM];
        s16x8 kf0 = *(const s16x8*)&kr[lg*8];
        s16x8 kf1 = *(const s16x8*)&kr[32 + lg*8];
        f32x4 st = {};
        st = __builtin_amdgcn_mfma_f32_16x16x32_bf16(kf0, qA0, st, 0,0,0);
        st = __builtin_amdgcn_mfma_f32_16x16x32_bf16(kf1, qA1, st, 0,0,0);
        s16x4 vv[4];
        #pragma unroll
        for (int f = 0; f < 4; ++f)
            vv[f] = *(const s16x4*)&Vb2[(size_t)(f*16 + lq)*NKTOK + 768 + lg*4];
        s16x4 pbv;
        float rs = 0.f;
        #pragma unroll
        for (int r = 0; r < 4; ++r) {
            float s = st[r];
            float e = __builtin_amdgcn_exp2f(fabsf(s));
            rs += e;
            pbv[r] = (short)f2bf_rn(copysignf(e, s));
        }
        ls += rs;
        #pragma unroll
        for (int f = 0; f < 4; ++f)
            oacc[f] = __builtin_amdgcn_mfma_f32_16x16x16bf16_1k(vv[f], pbv, oacc[f], 0,0,0);
    }
    if (wq0 < NQTOK) {
        float lr2 = ls;
        lr2 += __shfl_xor(lr2, 16);
        lr2 += __shfl_xor(lr2, 32);
        float inv = 1.f / lr2;
        unsigned short* cb = ctx + ((size_t)b*NQTOK + wq0 + lq)*NC + h*HDIM;
        #pragma unroll
        for (int f = 0; f < 4; ++f) {
            s16x4 o;
            #pragma unroll
            for (int r = 0; r < 4; ++r) o[r] = (short)f2bf(oacc[f][r] * inv);
            *(s16x4*)&cb[f*16 + lg*4] = o;
        }
    }
    #undef LOADT
    #undef WRITET
}

extern "C" void kernel_launch(void* const* d_in, const int* in_sizes, int n_in,
                              void* d_out, int out_size, void* d_ws, size_t ws_size,
                              hipStream_t stream)
{
    (void)in_sizes; (void)n_in; (void)out_size; (void)ws_size;
    const float* x      = (const float*)d_in[0];
    const float* q_w    = (const float*)d_in[3];
    const float* q_b    = (const float*)d_in[4];
    const float* k_w    = (const float*)d_in[5];
    const float* k_b    = (const float*)d_in[6];
    const float* v_w    = (const float*)d_in[7];
    const float* v_b    = (const float*)d_in[8];
    const float* q_dw_w = (const float*)d_in[9];
    const float* q_dw_b = (const float*)d_in[10];
    const float* k_dw_w = (const float*)d_in[11];
    const float* k_dw_b = (const float*)d_in[12];
    const float* v_dw_w = (const float*)d_in[13];
    const float* v_dw_b = (const float*)d_in[14];
    const float* proj_w = (const float*)d_in[15];
    const float* proj_b = (const float*)d_in[16];
    float* outf = (float*)d_out;
    unsigned short* ws  = (unsigned short*)d_ws;

    const size_t nQ  = (size_t)NB*NQTOK*NC;   // 9,633,792 elems
    const size_t nKc = (size_t)NB*NKTOK*NC;   // 2,408,448 elems
    unsigned short* preQ = ws;                // bf16 pre-conv Q
    unsigned short* preK = ws + nQ;           // bf16 pre-conv K; later ctx
    unsigned short* Kpk  = ws + 2*nQ;         // bf16 post-conv K, head-packed (bh,k,64)
    unsigned short* Vt   = Kpk + nKc;         // bf16 post-conv V, transposed (bh,d,k)
    unsigned short* wbf  = Vt + nKc;          // bf16 [4][384*384] dense weights
    float* wtab = (float*)(wbf + (size_t)4*NC*NC);   // [3][9][384] dw weights transposed
    float* ball = wtab + 3*9*NC;              // [4][384] biases
    unsigned short* preV = (unsigned short*)d_out;          // d_out lower half
    unsigned short* xbf  = ((unsigned short*)d_out) + nQ;   // d_out upper half: bf16 x
    unsigned short* Qc   = xbf;               // post-conv Q reuses upper half (xbf dead)
    unsigned short* ctx  = preK;              // reuse preK after k-conv

    // 0. fused prep: x->bf16, 4 dense weights->bf16, dw-weight transpose, bias gather
    prep_all<<<dim3(5039), dim3(256), 0, stream>>>(
        x, q_w, k_w, v_w, proj_w, q_b, k_b, v_b, proj_b,
        q_dw_w, k_dw_w, v_dw_w, xbf, wbf, wtab, ball);
    // 1. QKV projections (bf16 x bf16), 256x128 tiles: Q->preQ, K->preK, V->preV(d_out lo)
    gemm_bt_bf<false><<<dim3(98*9), dim3(512), 0, stream>>>(
        xbf, wbf, ball, preQ, preK, preV, nullptr, 9);
    // 2. all three depthwise convs fused (Qc -> d_out upper half; no overlap with preV)
    dwconv_all<<<dim3(7056), dim3(256), 0, stream>>>(
        preK, preV, preQ,
        wtab + 1*9*NC, wtab + 2*9*NC, wtab + 0*9*NC,
        k_dw_b, v_dw_b, q_dw_b, Kpk, Vt, Qc);
    // 3. attention: 624 = 48 bh x 13 q-tiles of 256 (16 waves x 16 q)
    attn_fwd<<<dim3(624), dim3(1024), 0, stream>>>(Qc, Kpk, Vt, ctx);
    // 4. output projection (256x128 tiles) -> f32 d_out
    gemm_bt_bf<true><<<dim3(98*3), dim3(512), 0, stream>>>(
        ctx, wbf + (size_t)3*NC*NC, ball + 3*NC, nullptr, nullptr, nullptr, outf, 3);
}

// Round 23
// 164.155 us; speedup vs baseline: 1.0790x; 1.0790x over previous
//
#include <hip/hip_runtime.h>
#include <hip/hip_bf16.h>
#include <stdint.h>

typedef __attribute__((ext_vector_type(4))) float f32x4;
typedef __attribute__((ext_vector_type(8))) short s16x8;
typedef __attribute__((ext_vector_type(4))) short s16x4;
typedef __attribute__((ext_vector_type(8))) unsigned short u16x8;

#define NB 8
#define HH 56
#define WW0 56
#define NC 384
#define NQTOK (HH*WW0)     // 3136
#define NKTOK 784
#define NHEAD 6
#define HDIM 64
// scale folded into q-conv: (1/sqrt(64)) * log2(e)
#define QSCALE 0.18033688f

__device__ __forceinline__ float bf2f(unsigned short u) {
    union { unsigned int i; float f; } x; x.i = ((unsigned int)u) << 16; return x.f;
}
__device__ __forceinline__ unsigned short f2bf(float f) {
    union { float f; unsigned int i; } x; x.f = f;
    unsigned int r = x.i + 0x7FFFu + ((x.i >> 16) & 1u);
    return (unsigned short)(r >> 16);
}
// round-half-up bf16: 2 ops vs RNE's 5; differs only on exact ties (P-packing only)
__device__ __forceinline__ unsigned short f2bf_rn(float f) {
    union { float f; unsigned int i; } x; x.f = f;
    return (unsigned short)((x.i + 0x8000u) >> 16);
}

// ---------- fused prep kernel (range-dispatched) ----------
__global__ __launch_bounds__(256) void prep_all(
    const float* __restrict__ x,
    const float* __restrict__ qw, const float* __restrict__ kw,
    const float* __restrict__ vw, const float* __restrict__ pw,
    const float* __restrict__ qb, const float* __restrict__ kb,
    const float* __restrict__ vb, const float* __restrict__ pb,
    const float* __restrict__ qdw, const float* __restrict__ kdw, const float* __restrict__ vdw,
    unsigned short* __restrict__ xbf, unsigned short* __restrict__ wbf,
    float* __restrict__ wtab, float* __restrict__ ball)
{
    const int bid = blockIdx.x;
    const int t = threadIdx.x;
    if (bid < 4704) {
        int i = bid*256 + t;
        f32x4 a0 = *(const f32x4*)&x[(size_t)i*8];
        f32x4 a1 = *(const f32x4*)&x[(size_t)i*8 + 4];
        u16x8 p;
        #pragma unroll
        for (int j = 0; j < 4; ++j) { p[j] = f2bf(a0[j]); p[j+4] = f2bf(a1[j]); }
        *(u16x8*)&xbf[(size_t)i*8] = p;
    } else if (bid < 4992) {
        int i = (bid - 4704)*256 + t;
        int m = i / 18432;
        const float* s = (m==0) ? qw : ((m==1) ? kw : ((m==2) ? vw : pw));
        int r = i - m*18432;
        f32x4 a0 = *(const f32x4*)&s[(size_t)r*8];
        f32x4 a1 = *(const f32x4*)&s[(size_t)r*8 + 4];
        u16x8 p;
        #pragma unroll
        for (int j = 0; j < 4; ++j) { p[j] = f2bf(a0[j]); p[j+4] = f2bf(a1[j]); }
        *(u16x8*)&wbf[(size_t)i*8] = p;
    } else {
        int j = (bid - 4992)*256 + t;
        if (j < 3*9*NC) {
            int m = j / (9*NC); int r = j - m*(9*NC);
            int tap = r / NC; int c = r - tap*NC;
            const float* src = (m==0) ? qdw : ((m==1) ? kdw : vdw);
            wtab[j] = src[c*9 + tap];
        } else {
            int jj = j - 3*9*NC;
            if (jj < 4*NC) {
                int m = jj / NC, r = jj - m*NC;
                ball[jj] = ((m==0) ? qb : ((m==1) ? kb : ((m==2) ? vb : pb)))[r];
            }
        }
    }
}

// ---------- GEMM: 256x128 tile, BK=64, 8 waves (4x2), XOR-swizzled LDS ----------
template<bool OUT_F32>
__global__ __launch_bounds__(512) void gemm_bt_bf(
    const unsigned short* __restrict__ A,
    const unsigned short* __restrict__ Wall,  // [nmat][384*384] bf16
    const float* __restrict__ Ball,           // [nmat][384] f32
    unsigned short* __restrict__ Oa, unsigned short* __restrict__ Ob, unsigned short* __restrict__ Oc,
    float* __restrict__ Of,
    int ntiles)
{
    __shared__ unsigned short lA[256*64];   // 32 KB
    __shared__ unsigned short lW[128*64];   // 16 KB
    char* lAb = (char*)lA;
    char* lWb = (char*)lW;
    const int bid = blockIdx.x;
    const int nt = bid % ntiles;      // nt-major: A-tile reuse temporally local
    const int mt = bid / ntiles;
    const int mat = nt / 3;
    const int ncol = nt - mat*3;
    const unsigned short* W = Wall + (size_t)mat*NC*NC;
    const float* Bsel = Ball + mat*NC;
    unsigned short* Osel = (mat==0) ? Oa : ((mat==1) ? Ob : Oc);
    const int Mbase = mt*256, Nbase = ncol*128;
    const int t = threadIdx.x;
    const int w = t >> 6, l = t & 63;
    const int wr = w >> 1, wc = w & 1;       // wr 0..3, wc 0..1
    const int lr = l & 15, lg = l >> 4;
    const int swg = (lr & 7) << 4;

    f32x4 acc[4][4] = {};
    for (int kt = 0; kt < 6; ++kt) {
        __syncthreads();
        #pragma unroll
        for (int i = 0; i < 4; ++i) {        // A: 2048 chunks of 16B
            int c = i*512 + t;
            int row = c >> 3, c8 = c & 7;
            int sdst = row*128 + ((c8*16) ^ ((row & 7) << 4));
            *(u16x8*)(lAb + sdst) = *(const u16x8*)&A[(size_t)(Mbase+row)*NC + kt*64 + c8*8];
        }
        #pragma unroll
        for (int i = 0; i < 2; ++i) {        // W: 1024 chunks
            int c = i*512 + t;
            int row = c >> 3, c8 = c & 7;
            int sdst = row*128 + ((c8*16) ^ ((row & 7) << 4));
            *(u16x8*)(lWb + sdst) = *(const u16x8*)&W[(size_t)(Nbase+row)*NC + kt*64 + c8*8];
        }
        __syncthreads();
        #pragma unroll
        for (int kk = 0; kk < 2; ++kk) {
            s16x8 af[4], bfr[4];
            #pragma unroll
            for (int m = 0; m < 4; ++m)
                af[m] = *(const s16x8*)(lAb + (wr*64 + m*16 + lr)*128 + ((kk*64 + lg*16) ^ swg));
            #pragma unroll
            for (int n = 0; n < 4; ++n)
                bfr[n] = *(const s16x8*)(lWb + (wc*64 + n*16 + lr)*128 + ((kk*64 + lg*16) ^ swg));
            #pragma unroll
            for (int m = 0; m < 4; ++m)
                #pragma unroll
                for (int n = 0; n < 4; ++n)
                    acc[m][n] = __builtin_amdgcn_mfma_f32_16x16x32_bf16(af[m], bfr[n], acc[m][n], 0, 0, 0);
        }
    }
    #pragma unroll
    for (int n = 0; n < 4; ++n) {
        int col = Nbase + wc*64 + n*16 + lr;
        float bias = Bsel[col];
        #pragma unroll
        for (int m = 0; m < 4; ++m) {
            int row0 = Mbase + wr*64 + m*16 + lg*4;
            #pragma unroll
            for (int r = 0; r < 4; ++r) {
                float vv = acc[m][n][r] + bias;
                if (OUT_F32) Of[(size_t)(row0 + r)*NC + col] = vv;
                else Osel[(size_t)(row0 + r)*NC + col] = f2bf(vv);
            }
        }
    }
}

// ---------- depthwise conv body (shared) ----------
// MODE: 0 = token layout (b,tok,384); 1 = head-packed K (bh,tok,64); 2 = transposed V (bh,d,tok)
template<int S, int HO, int WO, bool SCALE, int MODE>
__device__ __forceinline__ void dwconv_body(
    int idx,
    const unsigned short* __restrict__ in,
    const float* __restrict__ wt9,   // (9, NC) transposed
    const float* __restrict__ bias,  // (NC)
    unsigned short* __restrict__ outp)
{
    const int nc8 = NC/8;
    int c8 = idx % nc8; int rest = idx / nc8;
    int wo = rest % WO; rest /= WO;
    int ho = rest % HO; int b = rest / HO;
    int c0 = c8*8;
    f32x4 b0 = *(const f32x4*)&bias[c0];
    f32x4 b1 = *(const f32x4*)&bias[c0+4];
    float acc[8];
    #pragma unroll
    for (int j = 0; j < 4; ++j) { acc[j] = b0[j]; acc[j+4] = b1[j]; }
    #pragma unroll
    for (int kh = 0; kh < 3; ++kh) {
        int h = ho*S + kh - 1;
        if (h < 0 || h >= HH) continue;
        #pragma unroll
        for (int kw = 0; kw < 3; ++kw) {
            int ww = wo*S + kw - 1;
            if (ww < 0 || ww >= WW0) continue;
            int tap = kh*3 + kw;
            u16x8 xv = *(const u16x8*)&in[((size_t)b*(HH*WW0) + h*WW0 + ww)*NC + c0];
            f32x4 w0 = *(const f32x4*)&wt9[tap*NC + c0];
            f32x4 w1 = *(const f32x4*)&wt9[tap*NC + c0 + 4];
            #pragma unroll
            for (int j = 0; j < 4; ++j) {
                acc[j]   += bf2f(xv[j])   * w0[j];
                acc[j+4] += bf2f(xv[j+4]) * w1[j];
            }
        }
    }
    if (SCALE) {
        #pragma unroll
        for (int j = 0; j < 8; ++j) acc[j] *= QSCALE;
    }
    int tok = ho*WO + wo;
    int hh = c0 >> 6, d0 = c0 & 63;
    if (MODE == 0) {
        u16x8 ov;
        #pragma unroll
        for (int j = 0; j < 8; ++j) ov[j] = f2bf(acc[j]);
        *(u16x8*)&outp[((size_t)b*(HO*WO) + tok)*NC + c0] = ov;
    } else if (MODE == 1) {
        u16x8 ov;
        #pragma unroll
        for (int j = 0; j < 8; ++j) ov[j] = f2bf(acc[j]);
        *(u16x8*)&outp[((size_t)(b*NHEAD + hh)*(HO*WO) + tok)*HDIM + d0] = ov;
    } else {
        size_t base = ((size_t)(b*NHEAD + hh)*HDIM + d0)*(HO*WO) + tok;
        #pragma unroll
        for (int j = 0; j < 8; ++j)
            outp[base + (size_t)j*(HO*WO)] = f2bf(acc[j]);
    }
}

// all three convs fused: Qc lives in d_out UPPER half (disjoint from preV in lower half)
__global__ __launch_bounds__(256) void dwconv_all(
    const unsigned short* __restrict__ preK, const unsigned short* __restrict__ preV,
    const unsigned short* __restrict__ preQ,
    const float* __restrict__ wtK, const float* __restrict__ wtV, const float* __restrict__ wtQ,
    const float* __restrict__ biasK, const float* __restrict__ biasV, const float* __restrict__ biasQ,
    unsigned short* __restrict__ Kpk, unsigned short* __restrict__ Vt,
    unsigned short* __restrict__ Qc)
{
    const int bid = blockIdx.x;               // 7056 = 1176 + 1176 + 4704
    if (bid < 1176) {
        int idx = bid*256 + threadIdx.x;
        dwconv_body<2,28,28,false,1>(idx, preK, wtK, biasK, Kpk);
    } else if (bid < 2352) {
        int idx = (bid-1176)*256 + threadIdx.x;
        dwconv_body<2,28,28,false,2>(idx, preV, wtV, biasV, Vt);
    } else {
        int idx = (bid-2352)*256 + threadIdx.x;
        dwconv_body<1,56,56,true,0>(idx, preQ, wtQ, biasQ, Qc);
    }
}

// ---------- attention: 16 q-rows/wave, 8 waves/block (128 q), 1200 blocks, KVBLK=64 ----------
// sign(s)*softmax(|s|), no max tracking, per-lane deferred denominator.
// Rotated 2-deep pipeline; XOR swizzle byte^=((row&7)<<4); raw v_exp_f32.
// One staging pass serves 8 waves (thread stages exactly 1 K-chunk + 1 V-chunk);
// occupancy cap 4 blocks x 8 waves = 32 waves/CU.
__global__ __launch_bounds__(512) void attn_fwd(
    const unsigned short* __restrict__ Q,   // (NB, 3136, 384) bf16 pre-scaled by 0.125*log2e
    const unsigned short* __restrict__ Kpk, // (48, 784, 64) bf16 head-packed
    const unsigned short* __restrict__ Vt,  // (48, 64, 784) bf16 transposed
    unsigned short* __restrict__ ctx)       // (NB, 3136, 384) bf16
{
    __shared__ unsigned short lK[2][4096];
    __shared__ unsigned short lV[2][4096];
    const int bid = blockIdx.x;             // 1200 = 8 XCD * 6 bh * 25 qt
    const int xcd = bid & 7, slot = bid >> 3;
    const int bh = xcd*6 + slot/25;
    const int qt = slot % 25;
    const int b = bh / NHEAD, h = bh - b*NHEAD;
    const int t = threadIdx.x;
    const int w = t >> 6, l = t & 63;
    const int lq = l & 15, lg = l >> 4;
    const int wq0 = qt*128 + w*16;          // tail tile: waves w>=4 clamp + skip store
    const int wq0c = (wq0 > NQTOK-16) ? (NQTOK-16) : wq0;

    const unsigned short* Qb = Q + ((size_t)b*NQTOK + wq0c + lq)*NC + h*HDIM;
    s16x8 qA0 = *(const s16x8*)&Qb[lg*8];
    s16x8 qA1 = *(const s16x8*)&Qb[32 + lg*8];

    const char* Kg = (const char*)(Kpk + (size_t)bh*NKTOK*HDIM);
    const char* Vg = (const char*)(Vt + (size_t)bh*HDIM*NKTOK);
    char* lKb = (char*)lK;
    char* lVb = (char*)lV;

    // staging: 512 x 16B chunks per 8KB tile; ONE K-chunk + ONE V-chunk per thread
    const int cr = t >> 3;            // rows 0..63
    const int cc = (t & 7) * 16;      // byte col in 128B row
    const int dst = cr*128 + (cc ^ ((cr & 7) << 4));

    uint4 rk, rv;
    #define LOADT(kb) do { \
        rk = *(const uint4*)(Kg + (size_t)((kb) + cr)*128 + cc); \
        rv = *(const uint4*)(Vg + (size_t)cr*1568 + (kb)*2 + cc); \
    } while(0)
    #define WRITET(buf) do { \
        *(uint4*)(lKb + (buf)*8192 + dst) = rk; \
        *(uint4*)(lVb + (buf)*8192 + dst) = rv; \
    } while(0)

    const int swc = (lq & 7) << 4;
    const int ck0 = (lg*16) ^ swc;          // K frag half 0, byte col
    const int ck1 = (64 + lg*16) ^ swc;     // K frag half 1

    float ls = 0.f;
    f32x4 oacc[4] = {};

    // prologue: tile 0 -> buf0, tile 1 staged in regs
    LOADT(0);
    WRITET(0);
    LOADT(64);
    __syncthreads();

    for (int kt = 0; kt < 12; ++kt) {
        const int cur = kt & 1;
        if (kt < 11) {
            WRITET(cur ^ 1);                 // tile kt+1 (regs loaded last iter)
            if (kt < 10) LOADT((kt+2)*64);   // start loading tile kt+2
        }
        const char* Kl = lKb + cur*8192;
        const char* Vl = lVb + cur*8192;
        f32x4 st[4] = {};
        __builtin_amdgcn_s_setprio(1);
        #pragma unroll
        for (int kfr = 0; kfr < 4; ++kfr) {
            int rb = (kfr*16 + lq)*128;
            s16x8 kf0 = *(const s16x8*)(Kl + rb + ck0);
            s16x8 kf1 = *(const s16x8*)(Kl + rb + ck1);
            st[kfr] = __builtin_amdgcn_mfma_f32_16x16x32_bf16(kf0, qA0, st[kfr], 0,0,0);
            st[kfr] = __builtin_amdgcn_mfma_f32_16x16x32_bf16(kf1, qA1, st[kfr], 0,0,0);
        }
        __builtin_amdgcn_s_setprio(0);
        s16x4 pbv[4];
        {
            float rs = 0.f;
            #pragma unroll
            for (int kfr = 0; kfr < 4; ++kfr)
                #pragma unroll
                for (int r = 0; r < 4; ++r) {
                    float s = st[kfr][r];
                    float e = __builtin_amdgcn_exp2f(fabsf(s));
                    rs += e;
                    pbv[kfr][r] = (short)f2bf_rn(copysignf(e, s));
                }
            ls += rs;
        }
        __builtin_amdgcn_s_setprio(1);
        #pragma unroll
        for (int ks = 0; ks < 4; ++ks)
            #pragma unroll
            for (int f = 0; f < 4; ++f) {
                int va = (f*16 + lq)*128 + ((ks*32 + lg*8) ^ swc);
                s16x4 vvf = *(const s16x4*)(Vl + va);
                oacc[f] = __builtin_amdgcn_mfma_f32_16x16x16bf16_1k(vvf, pbv[ks], oacc[f], 0,0,0);
            }
        __builtin_amdgcn_s_setprio(0);
        if (kt < 11) __syncthreads();
    }
    // tail: k = 768..783 direct from global
    {
        const unsigned short* Kb2 = (const unsigned short*)Kg;
        const unsigned short* Vb2 = (const unsigned short*)Vg;
        const unsigned short* kr = &Kb2[(size_t)(768 + lq)*HDIM];
        s16x8 kf0 = *(const s16x8*)&kr[lg*8];
        s16x8 kf1 = *(const s16x8*)&kr[32 + lg*8];
        f32x4 st = {};
        st = __builtin_amdgcn_mfma_f32_16x16x32_bf16(kf0, qA0, st, 0,0,0);
        st = __builtin_amdgcn_mfma_f32_16x16x32_bf16(kf1, qA1, st, 0,0,0);
        s16x4 vv[4];
        #pragma unroll
        for (int f = 0; f < 4; ++f)
            vv[f] = *(const s16x4*)&Vb2[(size_t)(f*16 + lq)*NKTOK + 768 + lg*4];
        s16x4 pbv;
        float rs = 0.f;
        #pragma unroll
        for (int r = 0; r < 4; ++r) {
            float s = st[r];
            float e = __builtin_amdgcn_exp2f(fabsf(s));
            rs += e;
            pbv[r] = (short)f2bf_rn(copysignf(e, s));
        }
        ls += rs;
        #pragma unroll
        for (int f = 0; f < 4; ++f)
            oacc[f] = __builtin_amdgcn_mfma_f32_16x16x16bf16_1k(vv[f], pbv, oacc[f], 0,0,0);
    }
    if (wq0 < NQTOK) {
        float lr2 = ls;
        lr2 += __shfl_xor(lr2, 16);
        lr2 += __shfl_xor(lr2, 32);
        float inv = 1.f / lr2;
        unsigned short* cb = ctx + ((size_t)b*NQTOK + wq0 + lq)*NC + h*HDIM;
        #pragma unroll
        for (int f = 0; f < 4; ++f) {
            s16x4 o;
            #pragma unroll
            for (int r = 0; r < 4; ++r) o[r] = (short)f2bf(oacc[f][r] * inv);
            *(s16x4*)&cb[f*16 + lg*4] = o;
        }
    }
    #undef LOADT
    #undef WRITET
}

extern "C" void kernel_launch(void* const* d_in, const int* in_sizes, int n_in,
                              void* d_out, int out_size, void* d_ws, size_t ws_size,
                              hipStream_t stream)
{
    (void)in_sizes; (void)n_in; (void)out_size; (void)ws_size;
    const float* x      = (const float*)d_in[0];
    const float* q_w    = (const float*)d_in[3];
    const float* q_b    = (const float*)d_in[4];
    const float* k_w    = (const float*)d_in[5];
    const float* k_b    = (const float*)d_in[6];
    const float* v_w    = (const float*)d_in[7];
    const float* v_b    = (const float*)d_in[8];
    const float* q_dw_w = (const float*)d_in[9];
    const float* q_dw_b = (const float*)d_in[10];
    const float* k_dw_w = (const float*)d_in[11];
    const float* k_dw_b = (const float*)d_in[12];
    const float* v_dw_w = (const float*)d_in[13];
    const float* v_dw_b = (const float*)d_in[14];
    const float* proj_w = (const float*)d_in[15];
    const float* proj_b = (const float*)d_in[16];
    float* outf = (float*)d_out;
    unsigned short* ws  = (unsigned short*)d_ws;

    const size_t nQ  = (size_t)NB*NQTOK*NC;   // 9,633,792 elems
    const size_t nKc = (size_t)NB*NKTOK*NC;   // 2,408,448 elems
    unsigned short* preQ = ws;                // bf16 pre-conv Q
    unsigned short* preK = ws + nQ;           // bf16 pre-conv K; later ctx
    unsigned short* Kpk  = ws + 2*nQ;         // bf16 post-conv K, head-packed (bh,k,64)
    unsigned short* Vt   = Kpk + nKc;         // bf16 post-conv V, transposed (bh,d,k)
    unsigned short* wbf  = Vt + nKc;          // bf16 [4][384*384] dense weights
    float* wtab = (float*)(wbf + (size_t)4*NC*NC);   // [3][9][384] dw weights transposed
    float* ball = wtab + 3*9*NC;              // [4][384] biases
    unsigned short* preV = (unsigned short*)d_out;          // d_out lower half
    unsigned short* xbf  = ((unsigned short*)d_out) + nQ;   // d_out upper half: bf16 x
    unsigned short* Qc   = xbf;               // post-conv Q reuses upper half (xbf dead)
    unsigned short* ctx  = preK;              // reuse preK after k-conv

    // 0. fused prep: x->bf16, 4 dense weights->bf16, dw-weight transpose, bias gather
    prep_all<<<dim3(5039), dim3(256), 0, stream>>>(
        x, q_w, k_w, v_w, proj_w, q_b, k_b, v_b, proj_b,
        q_dw_w, k_dw_w, v_dw_w, xbf, wbf, wtab, ball);
    // 1. QKV projections (bf16 x bf16), 256x128 tiles: Q->preQ, K->preK, V->preV(d_out lo)
    gemm_bt_bf<false><<<dim3(98*9), dim3(512), 0, stream>>>(
        xbf, wbf, ball, preQ, preK, preV, nullptr, 9);
    // 2. all three depthwise convs fused (Qc -> d_out upper half; no overlap with preV)
    dwconv_all<<<dim3(7056), dim3(256), 0, stream>>>(
        preK, preV, preQ,
        wtab + 1*9*NC, wtab + 2*9*NC, wtab + 0*9*NC,
        k_dw_b, v_dw_b, q_dw_b, Kpk, Vt, Qc);
    // 3. attention: 1200 = 48 bh x 25 q-tiles of 128 (8 waves x 16 q)
    attn_fwd<<<dim3(1200), dim3(512), 0, stream>>>(Qc, Kpk, Vt, ctx);
    // 4. output projection (256x128 tiles) -> f32 d_out
    gemm_bt_bf<true><<<dim3(98*3), dim3(512), 0, stream>>>(
        ctx, wbf + (size_t)3*NC*NC, ball + 3*NC, nullptr, nullptr, nullptr, outf, 3);
}